// Round 3
// baseline (387.112 us; speedup 1.0000x reference)
//
#include <hip/hip_runtime.h>

#define NN 50000
#define NE 800000
#define NG 256
#define NB 256        // buckets
#define BW 196        // nodes per bucket
#define NBIN 200      // bin virtual blocks
#define EPB 4000      // edges per bin block: NBIN*EPB == NE
#define NGEMM 391     // gemm1 virtual blocks: (NN+127)/128
#define NFRONT (NGEMM + NBIN)
#define GRID 768      // 3 blocks/CU x 256 CUs; all resident (LDS allows 4/CU)
#define NAGG (NN / 16)
#define PAD 16        // ints: pad hot atomics to one 64B line
#define CAP 4608      // fixed region per bucket (mean 3136, +26 sigma)
#define WT_STRIDE 136 // LDS W-tile row stride in bf16

typedef __attribute__((ext_vector_type(8))) short bf16x8;
typedef __attribute__((ext_vector_type(4))) float f32x4;
typedef __attribute__((ext_vector_type(2))) float f32x2;

static __device__ __forceinline__ unsigned short f2b(float f) {
    unsigned int u = __float_as_uint(f);
    return (unsigned short)((u + 0x7FFFu + ((u >> 16) & 1u)) >> 16);
}
static __device__ __forceinline__ unsigned char f2e4m3(float f) {
    int p = __builtin_amdgcn_cvt_pk_fp8_f32(f, 0.f, 0, false);
    return (unsigned char)(p & 0xFF);
}

// Software grid barrier. Requires all GRID blocks resident (guaranteed:
// LDS 34.8KB -> 4 blocks/CU, launch_bounds(256,3) -> 3 blocks/CU used).
// Semantics mirror a kernel-launch boundary: release (wbL2) -> device-scope
// arrive -> RMW spin (coherence-point read, stale-L2-proof) -> acquire (inv).
static __device__ __forceinline__ void gbar(int* c, int target) {
    __syncthreads();                      // drains this block's vmcnt/lgkmcnt
    if (threadIdx.x == 0) {
        __threadfence();                  // agent release
        atomicAdd(c, 1);
        while (atomicAdd(c, 0) < target)  // RMW read at coherence point
            __builtin_amdgcn_s_sleep(8);
        __threadfence();                  // agent acquire
    }
    __syncthreads();
}

__global__ __launch_bounds__(256, 3) void k_all(
        const float* __restrict__ x, const float* __restrict__ W,
        unsigned char* __restrict__ h8,
        const int* __restrict__ src, const int* __restrict__ dst,
        int* __restrict__ bcur, unsigned int* __restrict__ ebuf,
        int* __restrict__ csr_src, int* __restrict__ rowptr,
        int* __restrict__ deg, float* __restrict__ dinv,
        const float* __restrict__ b1, const int* __restrict__ batch,
        int* __restrict__ pooled,
        const float* __restrict__ W2, const float* __restrict__ b2,
        float* __restrict__ out, int* __restrict__ bars) {
    __shared__ __align__(16) unsigned short Ws[128 * WT_STRIDE]; // 34816 B union
    const int tid = threadIdx.x;
    const int bid = blockIdx.x;

    // ================= P1: gemm1 (h8 = fp8(x @ W1), unscaled) || bin =========
    if (bid < NGEMM) {
#pragma unroll
        for (int p = 0; p < 64; ++p) {       // 256 thr x 64 = 16384 = 128x128
            int g = p * 256 + tid;
            int k = g >> 7, n = g & 127;     // coalesced read of W[k][n]
            Ws[n * WT_STRIDE + k] = f2b(W[g]);
        }
        __syncthreads();
        const int w = tid >> 6, lane = tid & 63;
        const int q = lane >> 4, lid = lane & 15;
        const int m0 = bid * 128 + w * 32;
        f32x4 acc[2][8];
#pragma unroll
        for (int rt = 0; rt < 2; ++rt)
#pragma unroll
            for (int jt = 0; jt < 8; ++jt) acc[rt][jt] = (f32x4){0.f, 0.f, 0.f, 0.f};
#pragma unroll
        for (int kt = 0; kt < 4; ++kt) {
            bf16x8 a[2];
#pragma unroll
            for (int rt = 0; rt < 2; ++rt) {
                int m = m0 + rt * 16 + lid;
                int k0 = kt * 32 + q * 8;
                float4 p0 = make_float4(0.f, 0.f, 0.f, 0.f), p1 = p0;
                if (m < NN) {
                    p0 = *(const float4*)(x + (size_t)m * 128 + k0);
                    p1 = *(const float4*)(x + (size_t)m * 128 + k0 + 4);
                }
                a[rt][0] = (short)f2b(p0.x); a[rt][1] = (short)f2b(p0.y);
                a[rt][2] = (short)f2b(p0.z); a[rt][3] = (short)f2b(p0.w);
                a[rt][4] = (short)f2b(p1.x); a[rt][5] = (short)f2b(p1.y);
                a[rt][6] = (short)f2b(p1.z); a[rt][7] = (short)f2b(p1.w);
            }
#pragma unroll
            for (int jt = 0; jt < 8; ++jt) {
                bf16x8 b = *(const bf16x8*)(Ws + (jt * 16 + lid) * WT_STRIDE + kt * 32 + q * 8);
                acc[0][jt] = __builtin_amdgcn_mfma_f32_16x16x32_bf16(a[0], b, acc[0][jt], 0, 0, 0);
                acc[1][jt] = __builtin_amdgcn_mfma_f32_16x16x32_bf16(a[1], b, acc[1][jt], 0, 0, 0);
            }
        }
        // C/D layout col=lane&15, row=q*4+reg; store fp8 unscaled
#pragma unroll
        for (int rt = 0; rt < 2; ++rt)
#pragma unroll
            for (int reg = 0; reg < 4; ++reg) {
                int gr = m0 + rt * 16 + q * 4 + reg;
                if (gr < NN) {
#pragma unroll
                    for (int jt = 0; jt < 8; ++jt)
                        h8[(size_t)gr * 128 + jt * 16 + lid] = f2e4m3(acc[rt][jt][reg]);
                }
            }
    } else if (bid < NFRONT) {
        // ---- binning path (first 3 KB of Ws as int scratch) ----
        int* lh = (int*)Ws;
        int* gb = lh + NB;
        int* lc = gb + NB;
        lh[tid] = 0; lc[tid] = 0;
        __syncthreads();
        int e0 = (bid - NGEMM) * EPB;
        for (int i = e0 + tid; i < e0 + EPB; i += 256)
            atomicAdd(&lh[(unsigned)dst[i] / BW], 1);
        __syncthreads();
        if (lh[tid]) gb[tid] = tid * CAP + atomicAdd(&bcur[tid * PAD], lh[tid]);
        __syncthreads();
        for (int i = e0 + tid; i < e0 + EPB; i += 256) { // dst re-read cache-hot
            int d = dst[i];
            int b = (unsigned)d / BW;
            int r = atomicAdd(&lc[b], 1);
            ebuf[gb[b] + r] = ((unsigned)(d - b * BW) << 17) | (unsigned)src[i];
        }
    }
    gbar(&bars[0], GRID);

    // ================= P2: per-bucket counting sort (+ pooled zero) ==========
    if (bid < NB) {
        if (tid < 128) pooled[bid * 128 + tid] = 0;
        int* hist = (int*)Ws;
        int* off = hist + NB;
        int* cur = off + NB;
        int* stage = cur + NB;              // CAP ints; total 21504 B <= 34816
        const int cnt = bcur[bid * PAD];
        const int ebeg = bid * CAP;
        const int nbase = bid * BW;
        hist[tid] = 0; cur[tid] = 0;
        __syncthreads();
        for (int i = tid; i < cnt; i += 256)
            atomicAdd(&hist[ebuf[ebeg + i] >> 17], 1);
        __syncthreads();
        int v = hist[tid];
        off[tid] = v;
        __syncthreads();
        for (int o = 1; o < NB; o <<= 1) {
            int u = (tid >= o) ? off[tid - o] : 0;
            __syncthreads();
            off[tid] += u;
            __syncthreads();
        }
        int ex = off[tid] - v;
        int gn = nbase + tid;
        if (tid < BW && gn < NN) {
            rowptr[gn] = ebeg + ex;
            deg[gn] = v;
            dinv[gn] = rsqrtf((float)(v + 1));
        }
        __syncthreads();
        off[tid] = ex;
        __syncthreads();
        for (int i = tid; i < cnt; i += 256) {
            unsigned int p = ebuf[ebeg + i];
            int l = p >> 17;
            int r = atomicAdd(&cur[l], 1);
            stage[off[l] + r] = (int)(p & 0x1FFFFu);
        }
        __syncthreads();
        for (int i = tid; i < cnt; i += 256)
            csr_src[ebeg + i] = stage[i];
    }
    gbar(&bars[1], GRID);

    // ================= P3: aggregation (grid-stride over 16-node tiles) ======
    {
        float* vals = (float*)Ws;                 // [16][128] = 8192 B
        int* bts = (int*)Ws + 2048;               // 16 ints
        const int qg = tid >> 4, ql = tid & 15;
        const int c = ql * 8;
        for (int vtile = bid; vtile < NAGG; vtile += GRID) {
            const int n = vtile * 16 + qg;        // NN = 3125*16, no tail
            if (ql == 0) bts[qg] = batch[n];
            const float dd = dinv[n];
            const int beg = rowptr[n];
            const int end = beg + deg[n];
            float a[8];
#pragma unroll
            for (int j = 0; j < 8; ++j) a[j] = 0.f;
#pragma unroll 4
            for (int i = beg; i < end; ++i) {
                int s = csr_src[i];
                float ds = dinv[s];
                uint2 v = *(const uint2*)(h8 + (size_t)s * 128 + c);
                f32x2 f0 = __builtin_amdgcn_cvt_pk_f32_fp8((int)v.x, false);
                f32x2 f1 = __builtin_amdgcn_cvt_pk_f32_fp8((int)v.x, true);
                f32x2 f2 = __builtin_amdgcn_cvt_pk_f32_fp8((int)v.y, false);
                f32x2 f3 = __builtin_amdgcn_cvt_pk_f32_fp8((int)v.y, true);
                a[0] = fmaf(ds, f0.x, a[0]); a[1] = fmaf(ds, f0.y, a[1]);
                a[2] = fmaf(ds, f1.x, a[2]); a[3] = fmaf(ds, f1.y, a[3]);
                a[4] = fmaf(ds, f2.x, a[4]); a[5] = fmaf(ds, f2.y, a[5]);
                a[6] = fmaf(ds, f3.x, a[6]); a[7] = fmaf(ds, f3.y, a[7]);
            }
            {
                // self loop: + dinv[n]*h[n], whole sum scaled by dinv[n]
                uint2 hv = *(const uint2*)(h8 + (size_t)n * 128 + c);
                f32x2 f0 = __builtin_amdgcn_cvt_pk_f32_fp8((int)hv.x, false);
                f32x2 f1 = __builtin_amdgcn_cvt_pk_f32_fp8((int)hv.x, true);
                f32x2 f2 = __builtin_amdgcn_cvt_pk_f32_fp8((int)hv.y, false);
                f32x2 f3 = __builtin_amdgcn_cvt_pk_f32_fp8((int)hv.y, true);
                float4 b0 = *(const float4*)(b1 + c);
                float4 b4 = *(const float4*)(b1 + c + 4);
                float r0 = fmaxf(dd * fmaf(dd, f0.x, a[0]) + b0.x, 0.f);
                float r1 = fmaxf(dd * fmaf(dd, f0.y, a[1]) + b0.y, 0.f);
                float r2 = fmaxf(dd * fmaf(dd, f1.x, a[2]) + b0.z, 0.f);
                float r3 = fmaxf(dd * fmaf(dd, f1.y, a[3]) + b0.w, 0.f);
                float r4 = fmaxf(dd * fmaf(dd, f2.x, a[4]) + b4.x, 0.f);
                float r5 = fmaxf(dd * fmaf(dd, f2.y, a[5]) + b4.y, 0.f);
                float r6 = fmaxf(dd * fmaf(dd, f3.x, a[6]) + b4.z, 0.f);
                float r7 = fmaxf(dd * fmaf(dd, f3.y, a[7]) + b4.w, 0.f);
                *(float4*)&vals[qg * 128 + c] = make_float4(r0, r1, r2, r3);
                *(float4*)&vals[qg * 128 + c + 4] = make_float4(r4, r5, r6, r7);
            }
            __syncthreads();
            if (tid < 128) {
                float m = vals[tid];
                int cur = bts[0];
#pragma unroll
                for (int ww = 1; ww < 16; ++ww) {
                    if (bts[ww] != cur) {
                        atomicMax(&pooled[cur * 128 + tid], __float_as_int(m));
                        cur = bts[ww];
                        m = vals[ww * 128 + tid];
                    } else {
                        m = fmaxf(m, vals[ww * 128 + tid]);
                    }
                }
                atomicMax(&pooled[cur * 128 + tid], __float_as_int(m));
            }
            __syncthreads();   // protect vals/bts before next tile
        }
    }
    gbar(&bars[2], GRID);

    // ================= P4: out = relu(pooled @ W2 + b2) ======================
    if (bid < NG / 4) {
        const int row = bid * 4 + (tid >> 6);
        const int col = tid & 63;
        const float* p = (const float*)pooled + row * 128;
        float acc = b2[col];
        for (int k = 0; k < 128; ++k) acc += p[k] * W2[k * 64 + col];
        out[row * 64 + col] = fmaxf(acc, 0.f);
    }
}

extern "C" void kernel_launch(void* const* d_in, const int* in_sizes, int n_in,
                              void* d_out, int out_size, void* d_ws, size_t ws_size,
                              hipStream_t stream) {
    const float* x     = (const float*)d_in[0];
    const int*   ei    = (const int*)d_in[1];   // [2, NE]: src row then dst row
    const int*   batch = (const int*)d_in[2];
    const float* W1    = (const float*)d_in[3];
    const float* b1    = (const float*)d_in[4];
    const float* W2    = (const float*)d_in[5];
    const float* b2    = (const float*)d_in[6];
    float* out = (float*)d_out;

    // ws layout (int units):
    // [zeroed: bcur NB*PAD | bars 48] pooled NG*128 | rowptr NN | deg NN |
    // dinv NN | csr_src NB*CAP | ebuf NB*CAP | h8 NN*128 bytes
    int*   bcur    = (int*)d_ws;
    int*   bars    = bcur + NB * PAD;
    int*   pooled  = bars + 48;
    int*   rowptr  = pooled + (size_t)NG * 128;
    int*   deg     = rowptr + NN;
    float* dinv    = (float*)(deg + NN);
    int*   csr_src = (int*)(dinv + NN);
    unsigned int* ebuf = (unsigned int*)(csr_src + (size_t)NB * CAP);
    unsigned char* h8  = (unsigned char*)(ebuf + (size_t)NB * CAP);

    size_t zbytes = ((size_t)NB * PAD + 48) * 4;
    hipMemsetAsync(d_ws, 0, zbytes, stream);

    const int* srcv = ei;
    const int* dstv = ei + NE;

    k_all<<<GRID, 256, 0, stream>>>(x, W1, h8, srcv, dstv, bcur, ebuf,
                                    csr_src, rowptr, deg, dinv, b1, batch,
                                    pooled, W2, b2, out, bars);
}

// Round 4
// 344.648 us; speedup vs baseline: 1.1232x; 1.1232x over previous
//
#include <hip/hip_runtime.h>

#define NN 50000
#define NE 800000
#define NG 256
#define NB 256        // buckets
#define BW 196        // nodes per bucket
#define NBIN 200      // bin virtual blocks
#define EPB 4000      // edges per bin block: NBIN*EPB == NE
#define NGEMM 391     // gemm1 virtual blocks: (NN+127)/128
#define NFRONT (NGEMM + NBIN)
#define GRID 512      // 2 blocks/CU x 256 CUs; residency GUARANTEED (see bounds)
#define NAGG (NN / 16)
#define PAD 16        // ints: pad hot atomics to one 64B line
#define CAP 4608      // fixed region per bucket (mean 3136, +26 sigma)
#define WT_STRIDE 136 // LDS W-tile row stride in bf16

typedef __attribute__((ext_vector_type(8))) short bf16x8;
typedef __attribute__((ext_vector_type(4))) float f32x4;
typedef __attribute__((ext_vector_type(2))) float f32x2;

static __device__ __forceinline__ unsigned short f2b(float f) {
    unsigned int u = __float_as_uint(f);
    return (unsigned short)((u + 0x7FFFu + ((u >> 16) & 1u)) >> 16);
}
static __device__ __forceinline__ unsigned char f2e4m3(float f) {
    int p = __builtin_amdgcn_cvt_pk_fp8_f32(f, 0.f, 0, false);
    return (unsigned char)(p & 0xFF);
}

// Software grid barrier, round-4 fix: arrive = one RMW per block; poll = agent
// scope atomic LOAD (no RMW storm on the line — round-3's 320us stall was 768
// blocks spinning atomicAdd(c,0) serialized at the coherence point).
// Residency: GRID=512 = 2 blocks/CU; launch_bounds(256,2) caps VGPR<=256 and
// LDS 34.8KB -> 4 blocks/CU, so >=2/CU is guaranteed by construction.
static __device__ __forceinline__ void gbar(int* c, int target) {
    __syncthreads();
    if (threadIdx.x == 0) {
        __threadfence();                       // agent release (wb L2)
        __hip_atomic_fetch_add(c, 1, __ATOMIC_RELAXED, __HIP_MEMORY_SCOPE_AGENT);
        while (__hip_atomic_load(c, __ATOMIC_RELAXED, __HIP_MEMORY_SCOPE_AGENT) < target)
            __builtin_amdgcn_s_sleep(8);
        __threadfence();                       // agent acquire (inv L2)
    }
    __syncthreads();
}

__global__ __launch_bounds__(256, 2) void k_all(
        const float* __restrict__ x, const float* __restrict__ W,
        unsigned char* __restrict__ h8,
        const int* __restrict__ src, const int* __restrict__ dst,
        int* __restrict__ bcur, unsigned int* __restrict__ ebuf,
        int* __restrict__ csr_src, int* __restrict__ rowptr,
        int* __restrict__ deg, float* __restrict__ dinv,
        const float* __restrict__ b1, const int* __restrict__ batch,
        int* __restrict__ pooled,
        const float* __restrict__ W2, const float* __restrict__ b2,
        float* __restrict__ out, int* __restrict__ bars) {
    __shared__ __align__(16) unsigned short Ws[128 * WT_STRIDE]; // 34816 B union
    const int tid = threadIdx.x;
    const int bid = blockIdx.x;

    // ===== P1: gemm1 (h8 = fp8(x @ W1), unscaled) || bin, grid-strided =======
    for (int v = bid; v < NFRONT; v += GRID) {
        if (v < NGEMM) {
            // ---- gemm1 chunk ----
#pragma unroll
            for (int p = 0; p < 64; ++p) {   // 256 thr x 64 = 16384 = 128x128
                int g = p * 256 + tid;
                int k = g >> 7, n = g & 127; // coalesced read of W[k][n]
                Ws[n * WT_STRIDE + k] = f2b(W[g]);
            }
            __syncthreads();
            const int w = tid >> 6, lane = tid & 63;
            const int q = lane >> 4, lid = lane & 15;
            const int m0 = v * 128 + w * 32;
            f32x4 acc[2][8];
#pragma unroll
            for (int rt = 0; rt < 2; ++rt)
#pragma unroll
                for (int jt = 0; jt < 8; ++jt) acc[rt][jt] = (f32x4){0.f, 0.f, 0.f, 0.f};
#pragma unroll
            for (int kt = 0; kt < 4; ++kt) {
                bf16x8 a[2];
#pragma unroll
                for (int rt = 0; rt < 2; ++rt) {
                    int m = m0 + rt * 16 + lid;
                    int k0 = kt * 32 + q * 8;
                    float4 p0 = make_float4(0.f, 0.f, 0.f, 0.f), p1 = p0;
                    if (m < NN) {
                        p0 = *(const float4*)(x + (size_t)m * 128 + k0);
                        p1 = *(const float4*)(x + (size_t)m * 128 + k0 + 4);
                    }
                    a[rt][0] = (short)f2b(p0.x); a[rt][1] = (short)f2b(p0.y);
                    a[rt][2] = (short)f2b(p0.z); a[rt][3] = (short)f2b(p0.w);
                    a[rt][4] = (short)f2b(p1.x); a[rt][5] = (short)f2b(p1.y);
                    a[rt][6] = (short)f2b(p1.z); a[rt][7] = (short)f2b(p1.w);
                }
#pragma unroll
                for (int jt = 0; jt < 8; ++jt) {
                    bf16x8 b = *(const bf16x8*)(Ws + (jt * 16 + lid) * WT_STRIDE + kt * 32 + q * 8);
                    acc[0][jt] = __builtin_amdgcn_mfma_f32_16x16x32_bf16(a[0], b, acc[0][jt], 0, 0, 0);
                    acc[1][jt] = __builtin_amdgcn_mfma_f32_16x16x32_bf16(a[1], b, acc[1][jt], 0, 0, 0);
                }
            }
            // C/D layout col=lane&15, row=q*4+reg; store fp8 unscaled
#pragma unroll
            for (int rt = 0; rt < 2; ++rt)
#pragma unroll
                for (int reg = 0; reg < 4; ++reg) {
                    int gr = m0 + rt * 16 + q * 4 + reg;
                    if (gr < NN) {
#pragma unroll
                        for (int jt = 0; jt < 8; ++jt)
                            h8[(size_t)gr * 128 + jt * 16 + lid] = f2e4m3(acc[rt][jt][reg]);
                    }
                }
        } else {
            // ---- binning chunk (first 3 KB of Ws as int scratch) ----
            int* lh = (int*)Ws;
            int* gb = lh + NB;
            int* lc = gb + NB;
            lh[tid] = 0; lc[tid] = 0;
            __syncthreads();
            int e0 = (v - NGEMM) * EPB;
            for (int i = e0 + tid; i < e0 + EPB; i += 256)
                atomicAdd(&lh[(unsigned)dst[i] / BW], 1);
            __syncthreads();
            if (lh[tid]) gb[tid] = tid * CAP + atomicAdd(&bcur[tid * PAD], lh[tid]);
            __syncthreads();
            for (int i = e0 + tid; i < e0 + EPB; i += 256) { // dst re-read hot
                int d = dst[i];
                int b = (unsigned)d / BW;
                int r = atomicAdd(&lc[b], 1);
                ebuf[gb[b] + r] = ((unsigned)(d - b * BW) << 17) | (unsigned)src[i];
            }
        }
        __syncthreads();   // WAR on Ws before next chunk
    }
    gbar(&bars[0], GRID);

    // ===== P2: per-bucket counting sort (+ pooled zero) ======================
    if (bid < NB) {
        if (tid < 128) pooled[bid * 128 + tid] = 0;
        int* hist = (int*)Ws;
        int* off = hist + NB;
        int* cur = off + NB;
        int* stage = cur + NB;              // CAP ints; total 21504 B <= 34816
        const int cnt = bcur[bid * PAD];
        const int ebeg = bid * CAP;
        const int nbase = bid * BW;
        hist[tid] = 0; cur[tid] = 0;
        __syncthreads();
        for (int i = tid; i < cnt; i += 256)
            atomicAdd(&hist[ebuf[ebeg + i] >> 17], 1);
        __syncthreads();
        int v = hist[tid];
        off[tid] = v;
        __syncthreads();
        for (int o = 1; o < NB; o <<= 1) {
            int u = (tid >= o) ? off[tid - o] : 0;
            __syncthreads();
            off[tid] += u;
            __syncthreads();
        }
        int ex = off[tid] - v;
        int gn = nbase + tid;
        if (tid < BW && gn < NN) {
            rowptr[gn] = ebeg + ex;
            deg[gn] = v;
            dinv[gn] = rsqrtf((float)(v + 1));
        }
        __syncthreads();
        off[tid] = ex;
        __syncthreads();
        for (int i = tid; i < cnt; i += 256) {
            unsigned int p = ebuf[ebeg + i];
            int l = p >> 17;
            int r = atomicAdd(&cur[l], 1);
            stage[off[l] + r] = (int)(p & 0x1FFFFu);
        }
        __syncthreads();
        for (int i = tid; i < cnt; i += 256)
            csr_src[ebeg + i] = stage[i];
    }
    gbar(&bars[1], GRID);

    // ===== P3: aggregation (grid-stride over 16-node tiles) ==================
    {
        float* vals = (float*)Ws;                 // [16][128] = 8192 B
        int* bts = (int*)Ws + 2048;               // 16 ints
        const int qg = tid >> 4, ql = tid & 15;
        const int c = ql * 8;
        for (int vtile = bid; vtile < NAGG; vtile += GRID) {
            const int n = vtile * 16 + qg;        // NN = 3125*16, no tail
            if (ql == 0) bts[qg] = batch[n];
            const float dd = dinv[n];
            const int beg = rowptr[n];
            const int end = beg + deg[n];
            float a[8];
#pragma unroll
            for (int j = 0; j < 8; ++j) a[j] = 0.f;
#pragma unroll 4
            for (int i = beg; i < end; ++i) {
                int s = csr_src[i];
                float ds = dinv[s];
                uint2 v = *(const uint2*)(h8 + (size_t)s * 128 + c);
                f32x2 f0 = __builtin_amdgcn_cvt_pk_f32_fp8((int)v.x, false);
                f32x2 f1 = __builtin_amdgcn_cvt_pk_f32_fp8((int)v.x, true);
                f32x2 f2 = __builtin_amdgcn_cvt_pk_f32_fp8((int)v.y, false);
                f32x2 f3 = __builtin_amdgcn_cvt_pk_f32_fp8((int)v.y, true);
                a[0] = fmaf(ds, f0.x, a[0]); a[1] = fmaf(ds, f0.y, a[1]);
                a[2] = fmaf(ds, f1.x, a[2]); a[3] = fmaf(ds, f1.y, a[3]);
                a[4] = fmaf(ds, f2.x, a[4]); a[5] = fmaf(ds, f2.y, a[5]);
                a[6] = fmaf(ds, f3.x, a[6]); a[7] = fmaf(ds, f3.y, a[7]);
            }
            {
                // self loop: + dinv[n]*h[n], whole sum scaled by dinv[n]
                uint2 hv = *(const uint2*)(h8 + (size_t)n * 128 + c);
                f32x2 f0 = __builtin_amdgcn_cvt_pk_f32_fp8((int)hv.x, false);
                f32x2 f1 = __builtin_amdgcn_cvt_pk_f32_fp8((int)hv.x, true);
                f32x2 f2 = __builtin_amdgcn_cvt_pk_f32_fp8((int)hv.y, false);
                f32x2 f3 = __builtin_amdgcn_cvt_pk_f32_fp8((int)hv.y, true);
                float4 b0 = *(const float4*)(b1 + c);
                float4 b4 = *(const float4*)(b1 + c + 4);
                float r0 = fmaxf(dd * fmaf(dd, f0.x, a[0]) + b0.x, 0.f);
                float r1 = fmaxf(dd * fmaf(dd, f0.y, a[1]) + b0.y, 0.f);
                float r2 = fmaxf(dd * fmaf(dd, f1.x, a[2]) + b0.z, 0.f);
                float r3 = fmaxf(dd * fmaf(dd, f1.y, a[3]) + b0.w, 0.f);
                float r4 = fmaxf(dd * fmaf(dd, f2.x, a[4]) + b4.x, 0.f);
                float r5 = fmaxf(dd * fmaf(dd, f2.y, a[5]) + b4.y, 0.f);
                float r6 = fmaxf(dd * fmaf(dd, f3.x, a[6]) + b4.z, 0.f);
                float r7 = fmaxf(dd * fmaf(dd, f3.y, a[7]) + b4.w, 0.f);
                *(float4*)&vals[qg * 128 + c] = make_float4(r0, r1, r2, r3);
                *(float4*)&vals[qg * 128 + c + 4] = make_float4(r4, r5, r6, r7);
            }
            __syncthreads();
            if (tid < 128) {
                float m = vals[tid];
                int cur = bts[0];
#pragma unroll
                for (int ww = 1; ww < 16; ++ww) {
                    if (bts[ww] != cur) {
                        atomicMax(&pooled[cur * 128 + tid], __float_as_int(m));
                        cur = bts[ww];
                        m = vals[ww * 128 + tid];
                    } else {
                        m = fmaxf(m, vals[ww * 128 + tid]);
                    }
                }
                atomicMax(&pooled[cur * 128 + tid], __float_as_int(m));
            }
            __syncthreads();   // protect vals/bts before next tile
        }
    }
    gbar(&bars[2], GRID);

    // ===== P4: out = relu(pooled @ W2 + b2) ==================================
    if (bid < NG / 4) {
        const int row = bid * 4 + (tid >> 6);
        const int col = tid & 63;
        const float* p = (const float*)pooled + row * 128;
        float acc = b2[col];
        for (int k = 0; k < 128; ++k) acc += p[k] * W2[k * 64 + col];
        out[row * 64 + col] = fmaxf(acc, 0.f);
    }
}

extern "C" void kernel_launch(void* const* d_in, const int* in_sizes, int n_in,
                              void* d_out, int out_size, void* d_ws, size_t ws_size,
                              hipStream_t stream) {
    const float* x     = (const float*)d_in[0];
    const int*   ei    = (const int*)d_in[1];   // [2, NE]: src row then dst row
    const int*   batch = (const int*)d_in[2];
    const float* W1    = (const float*)d_in[3];
    const float* b1    = (const float*)d_in[4];
    const float* W2    = (const float*)d_in[5];
    const float* b2    = (const float*)d_in[6];
    float* out = (float*)d_out;

    // ws layout (int units):
    // [zeroed: bcur NB*PAD | bars 48] pooled NG*128 | rowptr NN | deg NN |
    // dinv NN | csr_src NB*CAP | ebuf NB*CAP | h8 NN*128 bytes
    int*   bcur    = (int*)d_ws;
    int*   bars    = bcur + NB * PAD;
    int*   pooled  = bars + 48;
    int*   rowptr  = pooled + (size_t)NG * 128;
    int*   deg     = rowptr + NN;
    float* dinv    = (float*)(deg + NN);
    int*   csr_src = (int*)(dinv + NN);
    unsigned int* ebuf = (unsigned int*)(csr_src + (size_t)NB * CAP);
    unsigned char* h8  = (unsigned char*)(ebuf + (size_t)NB * CAP);

    size_t zbytes = ((size_t)NB * PAD + 48) * 4;
    hipMemsetAsync(d_ws, 0, zbytes, stream);

    const int* srcv = ei;
    const int* dstv = ei + NE;

    k_all<<<GRID, 256, 0, stream>>>(x, W1, h8, srcv, dstv, bcur, ebuf,
                                    csr_src, rowptr, deg, dinv, b1, batch,
                                    pooled, W2, b2, out, bars);
}

// Round 6
// 145.807 us; speedup vs baseline: 2.6550x; 2.3637x over previous
//
#include <hip/hip_runtime.h>

#define NN 50000
#define NE 800000
#define NG 256
#define NB 256        // buckets
#define BW 196        // nodes per bucket
#define NBIN 200      // k_bin blocks
#define EPB 4000      // edges per bin block: NBIN*EPB == NE
#define NGEMM 391     // gemm1 blocks: (NN+127)/128
#define PAD 16        // ints: pad hot atomics to one 64B line
#define CAP 4608      // fixed region per bucket (mean 3136, +26 sigma)
#define WT_STRIDE 136 // LDS W-tile row stride in bf16 (128x136 shorts = 34816B)
#define WBYTES (128 * WT_STRIDE * 2)

typedef __attribute__((ext_vector_type(8))) short bf16x8;
typedef __attribute__((ext_vector_type(4))) float f32x4;
typedef __attribute__((ext_vector_type(2))) float f32x2;

static __device__ __forceinline__ unsigned short f2b(float f) {
    unsigned int u = __float_as_uint(f);
    return (unsigned short)((u + 0x7FFFu + ((u >> 16) & 1u)) >> 16);
}
static __device__ __forceinline__ unsigned char f2e4m3(float f) {
    int p = __builtin_amdgcn_cvt_pk_fp8_f32(f, 0.f, 0, false);
    return (unsigned char)(p & 0xFF);
}

// 0) one-shot: W1 -> bf16, transposed + padded, the exact LDS image k_front
//    DMAs. wbf[n*WT_STRIDE + k] = bf16(W[k*128 + n]).
//    wbf ALIASES the csr_src region (lifetime: k_prep..k_front; csr_src is
//    first written in k_sort, after k_front completes) -> zero ws growth.
__global__ __launch_bounds__(256) void k_prep(const float* __restrict__ W,
                                              unsigned short* __restrict__ wbf) {
    int g = blockIdx.x * 256 + threadIdx.x;  // 64 blocks x 256 = 16384
    int k = g & 127, n = g >> 7;
    wbf[n * WT_STRIDE + k] = f2b(W[k * 128 + n]);  // coalesced 2B stores
}

// 1) FUSED front kernel: blocks [0, NGEMM) do h8 = fp8(x @ W1) (no dinv —
//    deferred to k_agg); blocks [NGEMM, ...) bin edges into ebuf regions.
__global__ __launch_bounds__(256) void k_front(const float* __restrict__ x,
                                               const unsigned short* __restrict__ wbf,
                                               unsigned char* __restrict__ h8,
                                               const int* __restrict__ src,
                                               const int* __restrict__ dst,
                                               int* __restrict__ bcur,
                                               unsigned int* __restrict__ ebuf) {
    __shared__ __align__(16) unsigned short Ws[128 * WT_STRIDE]; // 34816 B
    const int tid = threadIdx.x;

    if (blockIdx.x >= NGEMM) {
        // ---- binning path (first 3 KB of Ws as int scratch) ----
        int* lh = (int*)Ws;
        int* gb = lh + NB;
        int* lc = gb + NB;
        lh[tid] = 0; lc[tid] = 0;
        __syncthreads();
        int e0 = (blockIdx.x - NGEMM) * EPB;
        for (int i = e0 + tid; i < e0 + EPB; i += 256)
            atomicAdd(&lh[(unsigned)dst[i] / BW], 1);
        __syncthreads();
        if (lh[tid]) gb[tid] = tid * CAP + atomicAdd(&bcur[tid * PAD], lh[tid]);
        __syncthreads();
        for (int i = e0 + tid; i < e0 + EPB; i += 256) {  // dst re-read hot
            int d = dst[i];
            int b = (unsigned)d / BW;
            int r = atomicAdd(&lc[b], 1);
            ebuf[gb[b] + r] = ((unsigned)(d - b * BW) << 17) | (unsigned)src[i];
        }
        return;
    }

    // ---- gemm1 path: stage pre-converted W image via 16B global_load_lds ----
    // Per call: 64 lanes x 16B = 1024B, LDS dest = wave-uniform base + lane*16
    // (linear, matches the pre-transposed image). 34 chunks of 1024B total.
    {
        const int w = tid >> 6, lane = tid & 63;
        for (int o = w * 1024; o < WBYTES; o += 4096)
            __builtin_amdgcn_global_load_lds(wbf + (o >> 1) + lane * 8,
                                             Ws + (o >> 1), 16, 0, 0);
    }
    __syncthreads();
    const int w = tid >> 6, lane = tid & 63;
    const int q = lane >> 4, lid = lane & 15;
    const int m0 = blockIdx.x * 128 + w * 32;
    f32x4 acc[2][8];
#pragma unroll
    for (int rt = 0; rt < 2; ++rt)
#pragma unroll
        for (int jt = 0; jt < 8; ++jt) acc[rt][jt] = (f32x4){0.f, 0.f, 0.f, 0.f};

#pragma unroll
    for (int kt = 0; kt < 4; ++kt) {
        bf16x8 a[2];
#pragma unroll
        for (int rt = 0; rt < 2; ++rt) {
            int m = m0 + rt * 16 + lid;
            int k0 = kt * 32 + q * 8;
            float4 p0 = make_float4(0.f, 0.f, 0.f, 0.f), p1 = p0;
            if (m < NN) {
                p0 = *(const float4*)(x + (size_t)m * 128 + k0);
                p1 = *(const float4*)(x + (size_t)m * 128 + k0 + 4);
            }
            a[rt][0] = (short)f2b(p0.x); a[rt][1] = (short)f2b(p0.y);
            a[rt][2] = (short)f2b(p0.z); a[rt][3] = (short)f2b(p0.w);
            a[rt][4] = (short)f2b(p1.x); a[rt][5] = (short)f2b(p1.y);
            a[rt][6] = (short)f2b(p1.z); a[rt][7] = (short)f2b(p1.w);
        }
#pragma unroll
        for (int jt = 0; jt < 8; ++jt) {
            bf16x8 b = *(const bf16x8*)(Ws + (jt * 16 + lid) * WT_STRIDE + kt * 32 + q * 8);
            acc[0][jt] = __builtin_amdgcn_mfma_f32_16x16x32_bf16(a[0], b, acc[0][jt], 0, 0, 0);
            acc[1][jt] = __builtin_amdgcn_mfma_f32_16x16x32_bf16(a[1], b, acc[1][jt], 0, 0, 0);
        }
    }
    // epilogue: C/D layout col=lane&15, row=q*4+reg; store fp8 (unscaled)
#pragma unroll
    for (int rt = 0; rt < 2; ++rt)
#pragma unroll
        for (int reg = 0; reg < 4; ++reg) {
            int gr = m0 + rt * 16 + q * 4 + reg;
            if (gr < NN) {
#pragma unroll
                for (int jt = 0; jt < 8; ++jt)
                    h8[(size_t)gr * 128 + jt * 16 + lid] = f2e4m3(acc[rt][jt][reg]);
            }
        }
}

// 2) per-bucket counting sort into bucket-local csr region [b*CAP, ...).
__global__ __launch_bounds__(256) void k_sort(const unsigned int* __restrict__ ebuf,
                                              const int* __restrict__ bcur,
                                              int* __restrict__ csr_src,
                                              int* __restrict__ rowptr,
                                              int* __restrict__ deg,
                                              float* __restrict__ dinv) {
    __shared__ int hist[NB], off[NB], cur[NB];
    __shared__ int stage[CAP];
    const int t = threadIdx.x;
    const int b = blockIdx.x;
    const int cnt = bcur[b * PAD];
    const int ebeg = b * CAP;
    const int nbase = b * BW;
    hist[t] = 0; cur[t] = 0;
    __syncthreads();
    for (int i = t; i < cnt; i += 256)
        atomicAdd(&hist[ebuf[ebeg + i] >> 17], 1);
    __syncthreads();
    int v = hist[t];
    off[t] = v;
    __syncthreads();
    for (int o = 1; o < NB; o <<= 1) {
        int u = (t >= o) ? off[t - o] : 0;
        __syncthreads();
        off[t] += u;
        __syncthreads();
    }
    int ex = off[t] - v;
    int gn = nbase + t;
    if (t < BW && gn < NN) {
        rowptr[gn] = ebeg + ex;
        deg[gn] = v;
        dinv[gn] = rsqrtf((float)(v + 1));
    }
    __syncthreads();
    off[t] = ex;
    __syncthreads();
    for (int i = t; i < cnt; i += 256) {
        unsigned int p = ebuf[ebeg + i];
        int l = p >> 17;
        int r = atomicAdd(&cur[l], 1);
        stage[off[l] + r] = (int)(p & 0x1FFFFu);
    }
    __syncthreads();
    for (int i = t; i < cnt; i += 256)
        csr_src[ebeg + i] = stage[i];
}

// 3) aggregation: EIGHTH-wave (8 lanes x 16ch fp8 uint4) owns ONE dst node —
//    halves per-edge VMEM issue vs 16-lane/uint2. 32 nodes per block.
//    Fused per-edge dinv[s], bias+relu, sorted-batch max-pool.
__global__ __launch_bounds__(256) void k_agg(const unsigned char* __restrict__ h8,
                                             const int* __restrict__ csr_src,
                                             const int* __restrict__ rowptr,
                                             const int* __restrict__ deg,
                                             const float* __restrict__ dinv,
                                             const float* __restrict__ b1,
                                             const int* __restrict__ batch,
                                             int* __restrict__ pooled) {
    const int tid = threadIdx.x;
    const int g = tid >> 3, gl = tid & 7;
    const int n = blockIdx.x * 32 + g;
    __shared__ float vals[32][132];          // +4 pad: kill 512B-stride conflicts
    __shared__ int bts[32];
    const bool valid = (n < NN);
    if (gl == 0 && valid) bts[g] = batch[n];
    const float dd = valid ? dinv[n] : 0.f;
    int beg = 0, end = 0;
    if (valid) { beg = rowptr[n]; end = beg + deg[n]; }
    const int c = gl * 16;
    float a[16];
#pragma unroll
    for (int j = 0; j < 16; ++j) a[j] = 0.f;
#pragma unroll 4
    for (int i = beg; i < end; ++i) {
        int s = csr_src[i];
        float ds = dinv[s];
        uint4 v = *(const uint4*)(h8 + (size_t)s * 128 + c);
        f32x2 f0 = __builtin_amdgcn_cvt_pk_f32_fp8((int)v.x, false);
        f32x2 f1 = __builtin_amdgcn_cvt_pk_f32_fp8((int)v.x, true);
        f32x2 f2 = __builtin_amdgcn_cvt_pk_f32_fp8((int)v.y, false);
        f32x2 f3 = __builtin_amdgcn_cvt_pk_f32_fp8((int)v.y, true);
        f32x2 f4 = __builtin_amdgcn_cvt_pk_f32_fp8((int)v.z, false);
        f32x2 f5 = __builtin_amdgcn_cvt_pk_f32_fp8((int)v.z, true);
        f32x2 f6 = __builtin_amdgcn_cvt_pk_f32_fp8((int)v.w, false);
        f32x2 f7 = __builtin_amdgcn_cvt_pk_f32_fp8((int)v.w, true);
        a[0]  = fmaf(ds, f0.x, a[0]);  a[1]  = fmaf(ds, f0.y, a[1]);
        a[2]  = fmaf(ds, f1.x, a[2]);  a[3]  = fmaf(ds, f1.y, a[3]);
        a[4]  = fmaf(ds, f2.x, a[4]);  a[5]  = fmaf(ds, f2.y, a[5]);
        a[6]  = fmaf(ds, f3.x, a[6]);  a[7]  = fmaf(ds, f3.y, a[7]);
        a[8]  = fmaf(ds, f4.x, a[8]);  a[9]  = fmaf(ds, f4.y, a[9]);
        a[10] = fmaf(ds, f5.x, a[10]); a[11] = fmaf(ds, f5.y, a[11]);
        a[12] = fmaf(ds, f6.x, a[12]); a[13] = fmaf(ds, f6.y, a[13]);
        a[14] = fmaf(ds, f7.x, a[14]); a[15] = fmaf(ds, f7.y, a[15]);
    }
    if (valid) {
        // self loop: + dinv[n]*h[n], whole sum scaled by dinv[n]
        uint4 hv = *(const uint4*)(h8 + (size_t)n * 128 + c);
        f32x2 f0 = __builtin_amdgcn_cvt_pk_f32_fp8((int)hv.x, false);
        f32x2 f1 = __builtin_amdgcn_cvt_pk_f32_fp8((int)hv.x, true);
        f32x2 f2 = __builtin_amdgcn_cvt_pk_f32_fp8((int)hv.y, false);
        f32x2 f3 = __builtin_amdgcn_cvt_pk_f32_fp8((int)hv.y, true);
        f32x2 f4 = __builtin_amdgcn_cvt_pk_f32_fp8((int)hv.z, false);
        f32x2 f5 = __builtin_amdgcn_cvt_pk_f32_fp8((int)hv.z, true);
        f32x2 f6 = __builtin_amdgcn_cvt_pk_f32_fp8((int)hv.w, false);
        f32x2 f7 = __builtin_amdgcn_cvt_pk_f32_fp8((int)hv.w, true);
        float4 b0  = *(const float4*)(b1 + c);
        float4 b4  = *(const float4*)(b1 + c + 4);
        float4 b8  = *(const float4*)(b1 + c + 8);
        float4 b12 = *(const float4*)(b1 + c + 12);
        float r0  = fmaxf(dd * fmaf(dd, f0.x, a[0])  + b0.x,  0.f);
        float r1  = fmaxf(dd * fmaf(dd, f0.y, a[1])  + b0.y,  0.f);
        float r2  = fmaxf(dd * fmaf(dd, f1.x, a[2])  + b0.z,  0.f);
        float r3  = fmaxf(dd * fmaf(dd, f1.y, a[3])  + b0.w,  0.f);
        float r4  = fmaxf(dd * fmaf(dd, f2.x, a[4])  + b4.x,  0.f);
        float r5  = fmaxf(dd * fmaf(dd, f2.y, a[5])  + b4.y,  0.f);
        float r6  = fmaxf(dd * fmaf(dd, f3.x, a[6])  + b4.z,  0.f);
        float r7  = fmaxf(dd * fmaf(dd, f3.y, a[7])  + b4.w,  0.f);
        float r8  = fmaxf(dd * fmaf(dd, f4.x, a[8])  + b8.x,  0.f);
        float r9  = fmaxf(dd * fmaf(dd, f4.y, a[9])  + b8.y,  0.f);
        float r10 = fmaxf(dd * fmaf(dd, f5.x, a[10]) + b8.z,  0.f);
        float r11 = fmaxf(dd * fmaf(dd, f5.y, a[11]) + b8.w,  0.f);
        float r12 = fmaxf(dd * fmaf(dd, f6.x, a[12]) + b12.x, 0.f);
        float r13 = fmaxf(dd * fmaf(dd, f6.y, a[13]) + b12.y, 0.f);
        float r14 = fmaxf(dd * fmaf(dd, f7.x, a[14]) + b12.z, 0.f);
        float r15 = fmaxf(dd * fmaf(dd, f7.y, a[15]) + b12.w, 0.f);
        *(float4*)&vals[g][c]      = make_float4(r0, r1, r2, r3);
        *(float4*)&vals[g][c + 4]  = make_float4(r4, r5, r6, r7);
        *(float4*)&vals[g][c + 8]  = make_float4(r8, r9, r10, r11);
        *(float4*)&vals[g][c + 12] = make_float4(r12, r13, r14, r15);
    }
    __syncthreads();
    if (tid < 128) {
        const int cnt = min(32, NN - blockIdx.x * 32);
        float m = vals[0][tid];
        int cur = bts[0];
        for (int ww = 1; ww < cnt; ++ww) {
            if (bts[ww] != cur) {
                atomicMax(&pooled[cur * 128 + tid], __float_as_int(m));
                cur = bts[ww];
                m = vals[ww][tid];
            } else {
                m = fmaxf(m, vals[ww][tid]);
            }
        }
        atomicMax(&pooled[cur * 128 + tid], __float_as_int(m));
    }
}

// 4) out = relu(pooled @ W2 + b2)
__global__ __launch_bounds__(256) void k_gemm2(const float* __restrict__ pooled,
                                               const float* __restrict__ W2,
                                               const float* __restrict__ b2,
                                               float* __restrict__ out) {
    const int tid = threadIdx.x;
    const int row = blockIdx.x * 4 + (tid >> 6);
    const int col = tid & 63;
    const float* p = pooled + row * 128;
    float acc = b2[col];
    for (int k = 0; k < 128; ++k) acc += p[k] * W2[k * 64 + col];
    out[row * 64 + col] = fmaxf(acc, 0.f);
}

extern "C" void kernel_launch(void* const* d_in, const int* in_sizes, int n_in,
                              void* d_out, int out_size, void* d_ws, size_t ws_size,
                              hipStream_t stream) {
    const float* x     = (const float*)d_in[0];
    const int*   ei    = (const int*)d_in[1];   // [2, NE]: src row then dst row
    const int*   batch = (const int*)d_in[2];
    const float* W1    = (const float*)d_in[3];
    const float* b1    = (const float*)d_in[4];
    const float* W2    = (const float*)d_in[5];
    const float* b2    = (const float*)d_in[6];
    float* out = (float*)d_out;

    // ws layout (int units) — IDENTICAL footprint to the round-2 passing run:
    // [zeroed: pooled NG*128 | bcur NB*PAD] rowptr NN | deg NN | dinv NN |
    // csr_src NB*CAP | ebuf NB*CAP | h8 NN*128 bytes
    int*   pooled  = (int*)d_ws;
    int*   bcur    = pooled + (size_t)NG * 128;
    int*   rowptr  = bcur + NB * PAD;
    int*   deg     = rowptr + NN;
    float* dinv    = (float*)(deg + NN);
    int*   csr_src = (int*)(dinv + NN);
    unsigned int* ebuf = (unsigned int*)(csr_src + (size_t)NB * CAP);
    unsigned char* h8  = (unsigned char*)(ebuf + (size_t)NB * CAP);
    // wbf aliases the csr_src region (lifetimes disjoint: wbf dead after
    // k_front; csr_src first written in k_sort).
    unsigned short* wbf = (unsigned short*)csr_src;

    size_t zbytes = ((size_t)NG * 128 + NB * PAD) * 4;
    hipMemsetAsync(d_ws, 0, zbytes, stream);

    const int* srcv = ei;
    const int* dstv = ei + NE;

    k_prep<<<64, 256, 0, stream>>>(W1, wbf);
    k_front<<<NGEMM + NBIN, 256, 0, stream>>>(x, wbf, h8, srcv, dstv, bcur, ebuf);
    k_sort<<<NB, 256, 0, stream>>>(ebuf, bcur, csr_src, rowptr, deg, dinv);
    k_agg<<<(NN + 31) / 32, 256, 0, stream>>>(h8, csr_src, rowptr, deg, dinv, b1, batch, pooled);
    k_gemm2<<<NG / 4, 256, 0, stream>>>((const float*)pooled, W2, b2, out);
}